// Round 4
// baseline (1689.773 us; speedup 1.0000x reference)
//
#include <hip/hip_runtime.h>

// VectorQuantizerEMA  N=32768 K=8192 D=256  fp32
// Outputs: z_q_st[N*D], commitment[1], idx[N], new_embed[K*D], new_count[K], new_avg[K*D]
//
// Pass 1: single-term bf16 MFMA GEMM (zh*wh) -> approx score = cw - 2*zw,
//         per-row running min + windowed candidate collection (W=7e-4, worst-case safe).
// Pass 2: exact fp32-chain recompute of candidates (bit-exact vs numpy/OpenBLAS),
//         first-index tie-break. Epilogue via inverted index (no float atomics).

typedef __attribute__((ext_vector_type(8))) short short8;
typedef __attribute__((ext_vector_type(4))) float floatx4;

namespace {
constexpr int kN = 32768;
constexpr int kK = 8192;
constexpr int kD = 256;
constexpr int CAP = 64;
constexpr float WWIN = 7.0e-4f;  // >= 2*errA(2.9e-4 CS-worst) + 2*errS(3.2e-5)

// ---- workspace layout (bytes) ----
// zeroed region:
constexpr size_t OFF_HIST = 0;                               // int K
constexpr size_t OFF_COM  = OFF_HIST + (size_t)kK * 4;       // double
constexpr size_t OFF_NS   = OFF_COM + 8;                     // double
constexpr size_t OFF_GCNT = OFF_NS + 8;                      // uint N
constexpr size_t ZERO_BYTES = OFF_GCNT + (size_t)kN * 4;
// 0xFF region (rmin_map init = +inf under fmap):
constexpr size_t OFF_RMIN = (ZERO_BYTES + 63) & ~(size_t)63; // uint N
constexpr size_t FF_BYTES = (size_t)kN * 4;
// plain scratch:
constexpr size_t OFF_SZ   = OFF_RMIN + (size_t)kN * 4;       // float N
constexpr size_t OFF_CW   = OFF_SZ + (size_t)kN * 4;         // float K
constexpr size_t OFF_ZH   = OFF_CW + (size_t)kK * 4;         // u16 N*D (16MB)
constexpr size_t OFF_WH   = OFF_ZH + (size_t)kN * kD * 2;    // u16 K*D (4MB)
constexpr size_t OFF_CAND = OFF_WH + (size_t)kK * kD * 2;    // int2 N*CAP (16MB)
constexpr size_t OFF_IDX  = OFF_CAND + (size_t)kN * CAP * 8; // int N
constexpr size_t OFF_OFFS = OFF_IDX + (size_t)kN * 4;        // int K
constexpr size_t OFF_CUR  = OFF_OFFS + (size_t)kK * 4;       // int K
constexpr size_t OFF_ROWL = OFF_CUR + (size_t)kK * 4;        // int N
} // namespace

__device__ __forceinline__ unsigned fmap(float f) {
  unsigned u = __float_as_uint(f);
  return (u & 0x80000000u) ? ~u : (u | 0x80000000u);
}
__device__ __forceinline__ float funmap(unsigned m) {
  unsigned u = (m & 0x80000000u) ? (m & 0x7fffffffu) : ~m;
  return __uint_as_float(u);
}
__device__ __forceinline__ unsigned short f2bf(float f) {
  unsigned u = __float_as_uint(f);
  return (unsigned short)((u + 0x7fffu + ((u >> 16) & 1u)) >> 16);
}
__device__ __forceinline__ void gload16(const void* g, void* l) {
  __builtin_amdgcn_global_load_lds(
      (const __attribute__((address_space(1))) unsigned int*)g,
      (__attribute__((address_space(3))) unsigned int*)l, 16, 0, 0);
}

// ---------------- numpy AVX512 pairwise sum of squares ----------------
__device__ __forceinline__ float pw_block128_sq(const float* __restrict__ p) {
#pragma clang fp contract(off)
  float u[16];
#pragma unroll
  for (int l = 0; l < 16; ++l) {
    const float x0 = p[l] * p[l];
    const float x1 = p[16 + l] * p[16 + l];
    const float x2 = p[32 + l] * p[32 + l];
    const float x3 = p[48 + l] * p[48 + l];
    const float x4 = p[64 + l] * p[64 + l];
    const float x5 = p[80 + l] * p[80 + l];
    const float x6 = p[96 + l] * p[96 + l];
    const float x7 = p[112 + l] * p[112 + l];
    u[l] = ((x0 + x1) + (x2 + x3)) + ((x4 + x5) + (x6 + x7));
  }
  float t1[8], t2[4], t3[2];
#pragma unroll
  for (int l = 0; l < 8; ++l) t1[l] = u[l] + u[l + 8];
#pragma unroll
  for (int l = 0; l < 4; ++l) t2[l] = t1[l] + t1[l + 4];
#pragma unroll
  for (int l = 0; l < 2; ++l) t3[l] = t2[l] + t2[l + 2];
  return t3[0] + t3[1];
}

__global__ __launch_bounds__(256) void rowsum_sq(const float* __restrict__ x,
                                                 float* __restrict__ out) {
#pragma clang fp contract(off)
  const int r = blockIdx.x * 256 + threadIdx.x;
  const float* p = x + (size_t)r * kD;
  out[r] = pw_block128_sq(p) + pw_block128_sq(p + 128);
}

// ---------------- bf16 hi split only ----------------
__global__ __launch_bounds__(256) void split_hi(const float* __restrict__ x,
                                                unsigned short* __restrict__ hi) {
  const size_t i = (size_t)blockIdx.x * 256 + threadIdx.x;
  const float4 v = ((const float4*)x)[i];
  ushort4 h;
  h.x = f2bf(v.x);
  h.y = f2bf(v.y);
  h.z = f2bf(v.z);
  h.w = f2bf(v.w);
  ((ushort4*)hi)[i] = h;
}

// ---------------- MFMA filter pass ----------------
// grid 1024: (row-group 512) x (half 2). Block: 64 z-rows x 4096 codes
// (16 strips of 256). 4 waves, each 64 rows x 64 codes per strip.
__global__ __launch_bounds__(256, 2) void score_kernel(
    const unsigned short* __restrict__ zh, const unsigned short* __restrict__ wh,
    const float* __restrict__ cw, unsigned* __restrict__ gcnt,
    int2* __restrict__ gcand, unsigned* __restrict__ rmin_map) {
  __shared__ unsigned short Ah[64 * 64];    // 8 KB, XOR-swizzled 16B chunks
  __shared__ unsigned short Bh[256 * 64];   // 32 KB
  __shared__ unsigned ldsmin[64];

  const int tid = threadIdx.x;
  const int wid = tid >> 6;
  const int lane = tid & 63;
  const int l16 = lane & 15;
  const int quad = lane >> 4;
  const int m0 = (blockIdx.x >> 1) * 64;
  const int nb0 = (blockIdx.x & 1) * 16;

  if (tid < 64) ldsmin[tid] = 0xFFFFFFFFu;

  for (int nb = nb0; nb < nb0 + 16; ++nb) {
    const int n0 = nb * 256;
    floatx4 acc[4][4];
#pragma unroll
    for (int a = 0; a < 4; ++a)
#pragma unroll
      for (int b = 0; b < 4; ++b) acc[a][b] = (floatx4){0.f, 0.f, 0.f, 0.f};

    for (int kt = 0; kt < 4; ++kt) {
      const int d0 = kt * 64;
      __syncthreads();  // prior tile reads (and ldsmin init) complete
#pragma unroll
      for (int p = 0; p < 2; ++p) {            // A: 64 rows x 64 d
        const int q = p * 4 + wid;
        const int r = q * 8 + (lane >> 3);
        const int c = (lane & 7) ^ (r & 7);
        gload16(zh + (size_t)(m0 + r) * kD + d0 + c * 8, &Ah[q * 512]);
      }
#pragma unroll
      for (int p = 0; p < 8; ++p) {            // B: 256 codes x 64 d
        const int q = p * 4 + wid;
        const int r = q * 8 + (lane >> 3);
        const int c = (lane & 7) ^ (r & 7);
        gload16(wh + (size_t)(n0 + r) * kD + d0 + c * 8, &Bh[q * 512]);
      }
      __syncthreads();  // drain staging
#pragma unroll
      for (int kc = 0; kc < 2; ++kc) {
        short8 af[4], bfr[4];
#pragma unroll
        for (int mt = 0; mt < 4; ++mt) {
          const int row = mt * 16 + l16;
          const int j = (kc * 4 + quad) ^ (row & 7);
          af[mt] = *(const short8*)&Ah[row * 64 + j * 8];
        }
#pragma unroll
        for (int nt = 0; nt < 4; ++nt) {
          const int row = wid * 64 + nt * 16 + l16;
          const int j = (kc * 4 + quad) ^ (row & 7);
          bfr[nt] = *(const short8*)&Bh[row * 64 + j * 8];
        }
#pragma unroll
        for (int mt = 0; mt < 4; ++mt)
#pragma unroll
          for (int nt = 0; nt < 4; ++nt)
            acc[mt][nt] = __builtin_amdgcn_mfma_f32_16x16x32_bf16(
                af[mt], bfr[nt], acc[mt][nt], 0, 0, 0);
      }
    }

    // ---- epilogue: score = cw - 2*zw; running rowmin; windowed inserts ----
    float cwv[4];
#pragma unroll
    for (int nt = 0; nt < 4; ++nt) cwv[nt] = cw[n0 + wid * 64 + nt * 16 + l16];

    float rm[4][4];
#pragma unroll
    for (int mt = 0; mt < 4; ++mt)
#pragma unroll
      for (int r = 0; r < 4; ++r) {
        float mn = 3.4e38f;
#pragma unroll
        for (int nt = 0; nt < 4; ++nt) {
          const float s = fmaf(-2.0f, acc[mt][nt][r], cwv[nt]);
          acc[mt][nt][r] = s;
          mn = fminf(mn, s);
        }
        rm[mt][r] = mn;
      }
#pragma unroll
    for (int off = 1; off < 16; off <<= 1)
#pragma unroll
      for (int mt = 0; mt < 4; ++mt)
#pragma unroll
        for (int r = 0; r < 4; ++r)
          rm[mt][r] = fminf(rm[mt][r], __shfl_xor(rm[mt][r], off));
    if (l16 == 0) {
#pragma unroll
      for (int mt = 0; mt < 4; ++mt)
#pragma unroll
        for (int r = 0; r < 4; ++r)
          atomicMin(&ldsmin[mt * 16 + quad * 4 + r], fmap(rm[mt][r]));
    }
    __syncthreads();
#pragma unroll
    for (int mt = 0; mt < 4; ++mt)
#pragma unroll
      for (int r = 0; r < 4; ++r) {
        const int ml = mt * 16 + quad * 4 + r;
        const float thr = funmap(ldsmin[ml]) + WWIN;
        if (rm[mt][r] <= thr) {  // lane-local quick reject
#pragma unroll
          for (int nt = 0; nt < 4; ++nt) {
            const float s = acc[mt][nt][r];
            if (s <= thr) {
              const int m = m0 + ml;
              const int n = n0 + wid * 64 + nt * 16 + l16;
              const unsigned pos = atomicAdd(&gcnt[m], 1u);
              if (pos < CAP)
                gcand[(size_t)m * CAP + pos] = make_int2(__float_as_int(s), n);
            }
          }
        }
      }
  }
  __syncthreads();
  if (tid < 64) atomicMin(&rmin_map[m0 + tid], ldsmin[tid]);
}

// ---------------- exact fp32-chain refine (one wave per row) ----------------
__global__ __launch_bounds__(256) void refine_kernel(
    const float* __restrict__ z, const float* __restrict__ emb,
    const float* __restrict__ sz, const float* __restrict__ cw,
    const unsigned* __restrict__ gcnt, const int2* __restrict__ gcand,
    const unsigned* __restrict__ rmin_map, int* __restrict__ idxg,
    float* __restrict__ out_idx, int* __restrict__ hist) {
#pragma clang fp contract(off)
  const int wid = threadIdx.x >> 6;
  const int lane = threadIdx.x & 63;
  const int m = blockIdx.x * 4 + wid;
  const unsigned cnt = gcnt[m];
  const float srow = sz[m];
  const float thr = funmap(rmin_map[m]) + WWIN;
  const float* zrow = z + (size_t)m * kD;
  float bestd = 3.4e38f;
  int bestn = 0x7fffffff;
  if (cnt <= (unsigned)CAP) {
    if (lane < (int)cnt) {
      const int2 cd = gcand[(size_t)m * CAP + lane];
      const float sapp = __int_as_float(cd.x);
      const int n = cd.y;
      if (sapp <= thr) {  // prune inserts made under stale running min
        const float* wrow = emb + (size_t)n * kD;
        float a = 0.f;
        for (int d4 = 0; d4 < kD; d4 += 4) {
          const float4 zv = *(const float4*)&zrow[d4];
          const float4 wv = *(const float4*)&wrow[d4];
          a = __builtin_fmaf(zv.x, wv.x, a);
          a = __builtin_fmaf(zv.y, wv.y, a);
          a = __builtin_fmaf(zv.z, wv.z, a);
          a = __builtin_fmaf(zv.w, wv.w, a);
        }
        const float u = srow - 2.0f * a;
        bestd = u + cw[n];
        bestn = n;
      }
    }
  } else {
    // overflow fallback: exact scan of all K
    for (int base = 0; base < kK; base += 64) {
      const int n = base + lane;
      const float* wrow = emb + (size_t)n * kD;
      float a = 0.f;
      for (int d4 = 0; d4 < kD; d4 += 4) {
        const float4 zv = *(const float4*)&zrow[d4];
        const float4 wv = *(const float4*)&wrow[d4];
        a = __builtin_fmaf(zv.x, wv.x, a);
        a = __builtin_fmaf(zv.y, wv.y, a);
        a = __builtin_fmaf(zv.z, wv.z, a);
        a = __builtin_fmaf(zv.w, wv.w, a);
      }
      const float u = srow - 2.0f * a;
      const float dd = u + cw[n];
      if (dd < bestd) { bestd = dd; bestn = n; }
    }
  }
#pragma unroll
  for (int off = 1; off < 64; off <<= 1) {
    const float od = __shfl_xor(bestd, off);
    const int on = __shfl_xor(bestn, off);
    if (od < bestd || (od == bestd && on < bestn)) { bestd = od; bestn = on; }
  }
  if (lane == 0) {
    idxg[m] = bestn;
    out_idx[m] = (float)bestn;
    atomicAdd(&hist[bestn], 1);
  }
}

// ---------------- z_q_st + commitment ----------------
__global__ __launch_bounds__(256) void zq_commit(
    const float* __restrict__ z, const float* __restrict__ emb,
    const int* __restrict__ idxg, float* __restrict__ out_zq,
    double* __restrict__ commit) {
#pragma clang fp contract(off)
  const int n = blockIdx.x;
  const int d = threadIdx.x;
  const int k = idxg[n];
  const float zv = z[(size_t)n * kD + d];
  const float q = emb[(size_t)k * kD + d];
  out_zq[(size_t)n * kD + d] = zv + (q - zv);
  const float diff = zv - q;
  double v = (double)diff * (double)diff;
#pragma unroll
  for (int m = 32; m; m >>= 1) v += __shfl_xor(v, m);
  __shared__ double part[4];
  const int wv = d >> 6, lane = d & 63;
  if (lane == 0) part[wv] = v;
  __syncthreads();
  if (d == 0) atomicAdd(commit, part[0] + part[1] + part[2] + part[3]);
}

// ---------------- new_count + n = sum(new_count) ----------------
__global__ __launch_bounds__(256) void newcount_k(const int* __restrict__ hist,
                                                  const float* __restrict__ ec,
                                                  float* __restrict__ out_cnt,
                                                  double* __restrict__ nsum) {
#pragma clang fp contract(off)
  const int k = blockIdx.x * 256 + threadIdx.x;
  const float nc = 0.99f * ec[k] + 0.01f * (float)hist[k];
  out_cnt[k] = nc;
  double v = (double)nc;
#pragma unroll
  for (int m = 32; m; m >>= 1) v += __shfl_xor(v, m);
  __shared__ double part[4];
  const int wv = threadIdx.x >> 6, lane = threadIdx.x & 63;
  if (lane == 0) part[wv] = v;
  __syncthreads();
  if (threadIdx.x == 0) atomicAdd(nsum, part[0] + part[1] + part[2] + part[3]);
}

// ---------------- exclusive prefix over hist -> offs, cursor ----------------
__global__ __launch_bounds__(256) void prefix_k(const int* __restrict__ hist,
                                                int* __restrict__ offs,
                                                int* __restrict__ cursor) {
  __shared__ int tmp[256];
  __shared__ int chunkTotal;
  const int t = threadIdx.x;
  int running = 0;
  for (int c = 0; c < kK / 256; ++c) {
    const int v = hist[c * 256 + t];
    tmp[t] = v;
    __syncthreads();
    for (int off = 1; off < 256; off <<= 1) {
      const int add = (t >= off) ? tmp[t - off] : 0;
      __syncthreads();
      tmp[t] += add;
      __syncthreads();
    }
    const int excl = tmp[t] - v;
    offs[c * 256 + t] = running + excl;
    cursor[c * 256 + t] = running + excl;
    if (t == 255) chunkTotal = tmp[t];
    __syncthreads();
    running += chunkTotal;
  }
}

// ---------------- scatter rows into per-code lists ----------------
__global__ __launch_bounds__(256) void scatter_k(const int* __restrict__ idxg,
                                                 int* __restrict__ cursor,
                                                 int* __restrict__ rowlist) {
  const int r = blockIdx.x * 256 + threadIdx.x;
  const int k = idxg[r];
  const int pos = atomicAdd(&cursor[k], 1);
  rowlist[pos] = r;
}

// ---------------- new_avg + new_embed via gathered row sums ----------------
__global__ __launch_bounds__(256) void newavg_k(
    const float* __restrict__ z, const float* __restrict__ ea,
    const int* __restrict__ hist, const int* __restrict__ offs,
    const int* __restrict__ rowlist, const float* __restrict__ out_cnt,
    const double* __restrict__ nsum, float* __restrict__ out_emb,
    float* __restrict__ out_avg) {
#pragma clang fp contract(off)
  const int k = blockIdx.x;
  const int d = threadIdx.x;
  const int c = hist[k];
  const int off = offs[k];
  float s = 0.f;
  for (int j = 0; j < c; ++j)
    s += z[(size_t)rowlist[off + j] * kD + d];
  const size_t o = (size_t)k * kD + d;
  const float na = 0.99f * ea[o] + 0.01f * s;
  out_avg[o] = na;
  const float nf = (float)(*nsum);
  const float nc = out_cnt[k];
  const float keps = 0.08192f;  // fl(K * EPS)
  const float cs = (nc + 1e-5f) / (nf + keps) * nf;
  out_emb[o] = na / cs;
}

__global__ void fin_k(const double* __restrict__ commit,
                      float* __restrict__ out_com) {
  out_com[0] = (float)(0.25 * (*commit) / (double)((size_t)kN * kD));
}

extern "C" void kernel_launch(void* const* d_in, const int* in_sizes, int n_in,
                              void* d_out, int out_size, void* d_ws, size_t ws_size,
                              hipStream_t stream) {
  const float* z_e       = (const float*)d_in[0];
  const float* embedding = (const float*)d_in[1];
  const float* ema_count = (const float*)d_in[2];
  const float* ema_avg   = (const float*)d_in[3];

  char* ws = (char*)d_ws;
  int*    hist   = (int*)(ws + OFF_HIST);
  double* commit = (double*)(ws + OFF_COM);
  double* nsum   = (double*)(ws + OFF_NS);
  unsigned* gcnt = (unsigned*)(ws + OFF_GCNT);
  unsigned* rmin = (unsigned*)(ws + OFF_RMIN);
  float*  sz     = (float*)(ws + OFF_SZ);
  float*  cw     = (float*)(ws + OFF_CW);
  unsigned short* zh = (unsigned short*)(ws + OFF_ZH);
  unsigned short* wh = (unsigned short*)(ws + OFF_WH);
  int2*   gcand  = (int2*)(ws + OFF_CAND);
  int*    idxg   = (int*)(ws + OFF_IDX);
  int*    offs   = (int*)(ws + OFF_OFFS);
  int*    cursor = (int*)(ws + OFF_CUR);
  int*    rowlist= (int*)(ws + OFF_ROWL);

  float* out_zq  = (float*)d_out;
  float* out_com = out_zq + (size_t)kN * kD;
  float* out_idx = out_com + 1;
  float* out_emb = out_idx + kN;
  float* out_cnt = out_emb + (size_t)kK * kD;
  float* out_avg = out_cnt + kK;

  hipMemsetAsync(ws, 0, ZERO_BYTES, stream);
  hipMemsetAsync(ws + OFF_RMIN, 0xFF, FF_BYTES, stream);

  rowsum_sq<<<kN / 256, 256, 0, stream>>>(z_e, sz);
  rowsum_sq<<<kK / 256, 256, 0, stream>>>(embedding, cw);
  split_hi<<<(kN * kD / 4) / 256, 256, 0, stream>>>(z_e, zh);
  split_hi<<<(kK * kD / 4) / 256, 256, 0, stream>>>(embedding, wh);
  score_kernel<<<kN / 64 * 2, 256, 0, stream>>>(zh, wh, cw, gcnt, gcand, rmin);
  refine_kernel<<<kN / 4, 256, 0, stream>>>(z_e, embedding, sz, cw, gcnt,
                                            gcand, rmin, idxg, out_idx, hist);
  zq_commit<<<kN, 256, 0, stream>>>(z_e, embedding, idxg, out_zq, commit);
  newcount_k<<<kK / 256, 256, 0, stream>>>(hist, ema_count, out_cnt, nsum);
  prefix_k<<<1, 256, 0, stream>>>(hist, offs, cursor);
  scatter_k<<<kN / 256, 256, 0, stream>>>(idxg, cursor, rowlist);
  newavg_k<<<kK, 256, 0, stream>>>(z_e, ema_avg, hist, offs, rowlist, out_cnt,
                                   nsum, out_emb, out_avg);
  fin_k<<<1, 1, 0, stream>>>(commit, out_com);
}

// Round 5
// 1043.581 us; speedup vs baseline: 1.6192x; 1.6192x over previous
//
#include <hip/hip_runtime.h>

// VectorQuantizerEMA  N=32768 K=8192 D=256  fp32
// Outputs: z_q_st[N*D], commitment[1], idx[N], new_embed[K*D], new_count[K], new_avg[K*D]
//
// Pass 1: single-term fp16 MFMA GEMM (z16 * (w*2^14)16) -> approx score
//         = cw - 2^-13 * acc, per-row running min + windowed candidates (W=2e-4).
// Pass 2: compact candidates -> flat list -> exact fp32-chain dist per candidate
//         (bit-exact vs numpy/OpenBLAS), per-row atomicMin on (fmap(dist)<<32|n)
//         = first-index tie-break. Epilogue via inverted index, no hot atomics.

typedef _Float16 half8 __attribute__((ext_vector_type(8)));
typedef _Float16 half4 __attribute__((ext_vector_type(4)));
typedef __attribute__((ext_vector_type(4))) float floatx4;

namespace {
constexpr int kN = 32768;
constexpr int kK = 8192;
constexpr int kD = 256;
constexpr int CAP = 64;
constexpr int FLATCAP = 2097152;
constexpr float WWIN = 2.0e-4f;  // >= 2*eA(~1e-5 tail) + 2*eS(3.2e-5); 2.3x margin

// ---- workspace layout (bytes) ----
// zeroed region:
constexpr size_t OFF_HIST = 0;                                // int K
constexpr size_t OFF_NS   = OFF_HIST + (size_t)kK * 4;        // double
constexpr size_t OFF_GCNT = OFF_NS + 8;                       // uint N
constexpr size_t OFF_CCNT = OFF_GCNT + (size_t)kN * 4;        // int flat count
constexpr size_t ZERO_BYTES = OFF_CCNT + 8;
// 0xFF region (rkey init = max):
constexpr size_t OFF_RKEY = (ZERO_BYTES + 63) & ~(size_t)63;  // ull N
constexpr size_t FF_BYTES = (size_t)kN * 8;
// plain scratch:
constexpr size_t OFF_SZ   = OFF_RKEY + FF_BYTES;              // float N
constexpr size_t OFF_CW   = OFF_SZ + (size_t)kN * 4;          // float K
constexpr size_t OFF_Z16  = OFF_CW + (size_t)kK * 4;          // f16 N*D (16MB)
constexpr size_t OFF_W16  = OFF_Z16 + (size_t)kN * kD * 2;    // f16 K*D (4MB)
constexpr size_t OFF_CAND = OFF_W16 + (size_t)kK * kD * 2;    // int2 N*CAP (16MB)
constexpr size_t OFF_FLAT = OFF_CAND + (size_t)kN * CAP * 8;  // int2 FLATCAP (16MB)
constexpr size_t OFF_IDX  = OFF_FLAT + (size_t)FLATCAP * 8;   // int N
constexpr size_t OFF_OFFS = OFF_IDX + (size_t)kN * 4;         // int K
constexpr size_t OFF_CUR  = OFF_OFFS + (size_t)kK * 4;        // int K
constexpr size_t OFF_ROWL = OFF_CUR + (size_t)kK * 4;         // int N
constexpr size_t OFF_PART = OFF_ROWL + (size_t)kN * 4;        // double N (commit partials)
} // namespace

__device__ __forceinline__ unsigned fmap(float f) {
  unsigned u = __float_as_uint(f);
  return (u & 0x80000000u) ? ~u : (u | 0x80000000u);
}
__device__ __forceinline__ float funmap(unsigned m) {
  unsigned u = (m & 0x80000000u) ? (m & 0x7fffffffu) : ~m;
  return __uint_as_float(u);
}
__device__ __forceinline__ void gload16(const void* g, void* l) {
  __builtin_amdgcn_global_load_lds(
      (const __attribute__((address_space(1))) unsigned int*)g,
      (__attribute__((address_space(3))) unsigned int*)l, 16, 0, 0);
}

// ---------------- numpy AVX512 pairwise sum of squares ----------------
__device__ __forceinline__ float pw_block128_sq(const float* __restrict__ p) {
#pragma clang fp contract(off)
  float u[16];
#pragma unroll
  for (int l = 0; l < 16; ++l) {
    const float x0 = p[l] * p[l];
    const float x1 = p[16 + l] * p[16 + l];
    const float x2 = p[32 + l] * p[32 + l];
    const float x3 = p[48 + l] * p[48 + l];
    const float x4 = p[64 + l] * p[64 + l];
    const float x5 = p[80 + l] * p[80 + l];
    const float x6 = p[96 + l] * p[96 + l];
    const float x7 = p[112 + l] * p[112 + l];
    u[l] = ((x0 + x1) + (x2 + x3)) + ((x4 + x5) + (x6 + x7));
  }
  float t1[8], t2[4], t3[2];
#pragma unroll
  for (int l = 0; l < 8; ++l) t1[l] = u[l] + u[l + 8];
#pragma unroll
  for (int l = 0; l < 4; ++l) t2[l] = t1[l] + t1[l + 4];
#pragma unroll
  for (int l = 0; l < 2; ++l) t3[l] = t2[l] + t2[l + 2];
  return t3[0] + t3[1];
}

__global__ __launch_bounds__(256) void rowsum_sq(const float* __restrict__ x,
                                                 float* __restrict__ out) {
#pragma clang fp contract(off)
  const int r = blockIdx.x * 256 + threadIdx.x;
  const float* p = x + (size_t)r * kD;
  out[r] = pw_block128_sq(p) + pw_block128_sq(p + 128);
}

// ---------------- fp32 -> fp16 (optionally scaled by exact pow2) -----------
__global__ __launch_bounds__(256) void tofp16(const float* __restrict__ x,
                                              _Float16* __restrict__ out,
                                              float scale) {
  const size_t i = (size_t)blockIdx.x * 256 + threadIdx.x;
  const float4 v = ((const float4*)x)[i];
  half4 h;
  h.x = (_Float16)(v.x * scale);
  h.y = (_Float16)(v.y * scale);
  h.z = (_Float16)(v.z * scale);
  h.w = (_Float16)(v.w * scale);
  ((half4*)out)[i] = h;
}

// ---------------- MFMA filter pass ----------------
// grid 2048: (row-group 512) x (K-quarter 4). Block: 64 z-rows x 2048 codes
// (8 strips of 256). 4 waves, each 64 rows x 64 codes per strip.
__global__ __launch_bounds__(256, 2) void score_kernel(
    const _Float16* __restrict__ z16, const _Float16* __restrict__ w16,
    const float* __restrict__ cw, unsigned* __restrict__ gcnt,
    int2* __restrict__ gcand, unsigned* __restrict__ rmin_map) {
  __shared__ _Float16 Ah[64 * 64];    // 8 KB, XOR-swizzled 16B chunks
  __shared__ _Float16 Bh[256 * 64];   // 32 KB
  __shared__ unsigned ldsmin[64];

  const int tid = threadIdx.x;
  const int wid = tid >> 6;
  const int lane = tid & 63;
  const int l16 = lane & 15;
  const int quad = lane >> 4;
  const int m0 = (blockIdx.x >> 2) * 64;
  const int nb0 = (blockIdx.x & 3) * 8;

  if (tid < 64) ldsmin[tid] = 0xFFFFFFFFu;

  for (int nb = nb0; nb < nb0 + 8; ++nb) {
    const int n0 = nb * 256;
    floatx4 acc[4][4];
#pragma unroll
    for (int a = 0; a < 4; ++a)
#pragma unroll
      for (int b = 0; b < 4; ++b) acc[a][b] = (floatx4){0.f, 0.f, 0.f, 0.f};

    for (int kt = 0; kt < 4; ++kt) {
      const int d0 = kt * 64;
      __syncthreads();  // prior tile reads (and ldsmin init) complete
#pragma unroll
      for (int p = 0; p < 2; ++p) {            // A: 64 rows x 64 d
        const int q = p * 4 + wid;
        const int r = q * 8 + (lane >> 3);
        const int c = (lane & 7) ^ (r & 7);
        gload16(z16 + (size_t)(m0 + r) * kD + d0 + c * 8, &Ah[q * 512]);
      }
#pragma unroll
      for (int p = 0; p < 8; ++p) {            // B: 256 codes x 64 d
        const int q = p * 4 + wid;
        const int r = q * 8 + (lane >> 3);
        const int c = (lane & 7) ^ (r & 7);
        gload16(w16 + (size_t)(n0 + r) * kD + d0 + c * 8, &Bh[q * 512]);
      }
      __syncthreads();  // drain staging
#pragma unroll
      for (int kc = 0; kc < 2; ++kc) {
        half8 af[4], bfr[4];
#pragma unroll
        for (int mt = 0; mt < 4; ++mt) {
          const int row = mt * 16 + l16;
          const int j = (kc * 4 + quad) ^ (row & 7);
          af[mt] = *(const half8*)&Ah[row * 64 + j * 8];
        }
#pragma unroll
        for (int nt = 0; nt < 4; ++nt) {
          const int row = wid * 64 + nt * 16 + l16;
          const int j = (kc * 4 + quad) ^ (row & 7);
          bfr[nt] = *(const half8*)&Bh[row * 64 + j * 8];
        }
#pragma unroll
        for (int mt = 0; mt < 4; ++mt)
#pragma unroll
          for (int nt = 0; nt < 4; ++nt)
            acc[mt][nt] = __builtin_amdgcn_mfma_f32_16x16x32_f16(
                af[mt], bfr[nt], acc[mt][nt], 0, 0, 0);
      }
    }

    // ---- epilogue: score = cw - 2^-13*acc; running rowmin; windowed inserts
    float cwv[4];
#pragma unroll
    for (int nt = 0; nt < 4; ++nt) cwv[nt] = cw[n0 + wid * 64 + nt * 16 + l16];

    float rm[4][4];
#pragma unroll
    for (int mt = 0; mt < 4; ++mt)
#pragma unroll
      for (int r = 0; r < 4; ++r) {
        float mn = 3.4e38f;
#pragma unroll
        for (int nt = 0; nt < 4; ++nt) {
          // w was scaled by 2^14; -2 * 2^-14 = -2^-13 exactly
          const float s = fmaf(acc[mt][nt][r], -1.220703125e-4f, cwv[nt]);
          acc[mt][nt][r] = s;
          mn = fminf(mn, s);
        }
        rm[mt][r] = mn;
      }
#pragma unroll
    for (int off = 1; off < 16; off <<= 1)
#pragma unroll
      for (int mt = 0; mt < 4; ++mt)
#pragma unroll
        for (int r = 0; r < 4; ++r)
          rm[mt][r] = fminf(rm[mt][r], __shfl_xor(rm[mt][r], off));
    if (l16 == 0) {
#pragma unroll
      for (int mt = 0; mt < 4; ++mt)
#pragma unroll
        for (int r = 0; r < 4; ++r)
          atomicMin(&ldsmin[mt * 16 + quad * 4 + r], fmap(rm[mt][r]));
    }
    __syncthreads();
#pragma unroll
    for (int mt = 0; mt < 4; ++mt)
#pragma unroll
      for (int r = 0; r < 4; ++r) {
        const int ml = mt * 16 + quad * 4 + r;
        const float thr = funmap(ldsmin[ml]) + WWIN;
        if (rm[mt][r] <= thr) {  // lane-local quick reject
#pragma unroll
          for (int nt = 0; nt < 4; ++nt) {
            const float s = acc[mt][nt][r];
            if (s <= thr) {
              const int m = m0 + ml;
              const int n = n0 + wid * 64 + nt * 16 + l16;
              const unsigned pos = atomicAdd(&gcnt[m], 1u);
              if (pos < CAP)
                gcand[(size_t)m * CAP + pos] = make_int2(__float_as_int(s), n);
            }
          }
        }
      }
  }
  __syncthreads();
  if (tid < 64) atomicMin(&rmin_map[m0 + tid], ldsmin[tid]);
}

// ---------------- compact candidates into flat list (wave per row) --------
__global__ __launch_bounds__(256) void compact_kernel(
    const unsigned* __restrict__ gcnt, const int2* __restrict__ gcand,
    const unsigned* __restrict__ rmin_map, int2* __restrict__ flat,
    int* __restrict__ ccnt) {
  const int wid = threadIdx.x >> 6;
  const int lane = threadIdx.x & 63;
  const int m = blockIdx.x * 4 + wid;
  const unsigned cnt = gcnt[m];
  if (cnt <= (unsigned)CAP) {
    const float thr = funmap(rmin_map[m]) + WWIN;
    int n = 0;
    bool keep = false;
    if (lane < (int)cnt) {
      const int2 cd = gcand[(size_t)m * CAP + lane];
      keep = (__int_as_float(cd.x) <= thr);
      n = cd.y;
    }
    const unsigned long long mask = __ballot(keep);
    const int tot = __popcll(mask);
    int base = 0;
    if (lane == 0) base = atomicAdd(ccnt, tot);
    base = __shfl(base, 0);
    if (keep && base + tot <= FLATCAP) {
      const int rank = __popcll(mask & ((1ull << lane) - 1ull));
      flat[base + rank] = make_int2(m, n);
    }
  } else {
    // overflow (statistically never): emit all K codes for exact scan
    int base = 0;
    if (lane == 0) base = atomicAdd(ccnt, kK);
    base = __shfl(base, 0);
    if (base + kK <= FLATCAP)
      for (int j = lane; j < kK; j += 64) flat[base + j] = make_int2(m, j);
  }
}

// ---------------- exact fp32-chain dist per candidate ----------------
__global__ __launch_bounds__(256) void exact_kernel(
    const float* __restrict__ z, const float* __restrict__ emb,
    const float* __restrict__ sz, const float* __restrict__ cw,
    const int2* __restrict__ flat, const int* __restrict__ ccnt,
    unsigned long long* __restrict__ rkey) {
#pragma clang fp contract(off)
  int total = *ccnt;
  if (total > FLATCAP) total = FLATCAP;
  const int stride = gridDim.x * 256;
  for (int i = blockIdx.x * 256 + threadIdx.x; i < total; i += stride) {
    const int2 c = flat[i];
    const int m = c.x, n = c.y;
    const float* zrow = z + (size_t)m * kD;
    const float* wrow = emb + (size_t)n * kD;
    float a = 0.f;
    for (int d4 = 0; d4 < kD; d4 += 4) {
      const float4 zv = *(const float4*)&zrow[d4];
      const float4 wv = *(const float4*)&wrow[d4];
      a = __builtin_fmaf(zv.x, wv.x, a);
      a = __builtin_fmaf(zv.y, wv.y, a);
      a = __builtin_fmaf(zv.z, wv.z, a);
      a = __builtin_fmaf(zv.w, wv.w, a);
    }
    const float u = sz[m] - 2.0f * a;
    const float dist = u + cw[n];
    const unsigned long long key =
        ((unsigned long long)fmap(dist) << 32) | (unsigned)n;
    atomicMin(&rkey[m], key);  // first-index tie-break: equal dist -> lower n
  }
}

// ---------------- finalize idx + histogram ----------------
__global__ __launch_bounds__(256) void finalize_kernel(
    const unsigned long long* __restrict__ rkey, int* __restrict__ idxg,
    float* __restrict__ out_idx, int* __restrict__ hist) {
  const int m = blockIdx.x * 256 + threadIdx.x;
  const int n = (int)(rkey[m] & 0xffffffffu);
  idxg[m] = n;
  out_idx[m] = (float)n;
  atomicAdd(&hist[n], 1);
}

// ---------------- z_q_st + commitment partials (no hot atomics) -----------
__global__ __launch_bounds__(256) void zq_commit(
    const float* __restrict__ z, const float* __restrict__ emb,
    const int* __restrict__ idxg, float* __restrict__ out_zq,
    double* __restrict__ part_out) {
#pragma clang fp contract(off)
  const int n = blockIdx.x;
  const int d = threadIdx.x;
  const int k = idxg[n];
  const float zv = z[(size_t)n * kD + d];
  const float q = emb[(size_t)k * kD + d];
  out_zq[(size_t)n * kD + d] = zv + (q - zv);
  const float diff = zv - q;
  double v = (double)diff * (double)diff;
#pragma unroll
  for (int m = 32; m; m >>= 1) v += __shfl_xor(v, m);
  __shared__ double part[4];
  const int wv = d >> 6, lane = d & 63;
  if (lane == 0) part[wv] = v;
  __syncthreads();
  if (d == 0) part_out[n] = part[0] + part[1] + part[2] + part[3];
}

// ---------------- reduce commitment partials ----------------
__global__ __launch_bounds__(256) void reduce_commit(
    const double* __restrict__ part, float* __restrict__ out_com) {
  const int t = threadIdx.x;
  double s = 0.0;
  for (int i = t; i < kN; i += 256) s += part[i];
#pragma unroll
  for (int m = 32; m; m >>= 1) s += __shfl_xor(s, m);
  __shared__ double ws[4];
  if ((t & 63) == 0) ws[t >> 6] = s;
  __syncthreads();
  if (t == 0)
    out_com[0] =
        (float)(0.25 * (ws[0] + ws[1] + ws[2] + ws[3]) / (double)((size_t)kN * kD));
}

// ---------------- new_count + n = sum(new_count) ----------------
__global__ __launch_bounds__(256) void newcount_k(const int* __restrict__ hist,
                                                  const float* __restrict__ ec,
                                                  float* __restrict__ out_cnt,
                                                  double* __restrict__ nsum) {
#pragma clang fp contract(off)
  const int k = blockIdx.x * 256 + threadIdx.x;
  const float nc = 0.99f * ec[k] + 0.01f * (float)hist[k];
  out_cnt[k] = nc;
  double v = (double)nc;
#pragma unroll
  for (int m = 32; m; m >>= 1) v += __shfl_xor(v, m);
  __shared__ double part[4];
  const int wv = threadIdx.x >> 6, lane = threadIdx.x & 63;
  if (lane == 0) part[wv] = v;
  __syncthreads();
  if (threadIdx.x == 0) atomicAdd(nsum, part[0] + part[1] + part[2] + part[3]);
}

// ---------------- exclusive prefix over hist -> offs, cursor ----------------
__global__ __launch_bounds__(256) void prefix_k(const int* __restrict__ hist,
                                                int* __restrict__ offs,
                                                int* __restrict__ cursor) {
  __shared__ int tmp[256];
  __shared__ int chunkTotal;
  const int t = threadIdx.x;
  int running = 0;
  for (int c = 0; c < kK / 256; ++c) {
    const int v = hist[c * 256 + t];
    tmp[t] = v;
    __syncthreads();
    for (int off = 1; off < 256; off <<= 1) {
      const int add = (t >= off) ? tmp[t - off] : 0;
      __syncthreads();
      tmp[t] += add;
      __syncthreads();
    }
    const int excl = tmp[t] - v;
    offs[c * 256 + t] = running + excl;
    cursor[c * 256 + t] = running + excl;
    if (t == 255) chunkTotal = tmp[t];
    __syncthreads();
    running += chunkTotal;
  }
}

// ---------------- scatter rows into per-code lists ----------------
__global__ __launch_bounds__(256) void scatter_k(const int* __restrict__ idxg,
                                                 int* __restrict__ cursor,
                                                 int* __restrict__ rowlist) {
  const int r = blockIdx.x * 256 + threadIdx.x;
  const int k = idxg[r];
  const int pos = atomicAdd(&cursor[k], 1);
  rowlist[pos] = r;
}

// ---------------- new_avg + new_embed via gathered row sums ----------------
__global__ __launch_bounds__(256) void newavg_k(
    const float* __restrict__ z, const float* __restrict__ ea,
    const int* __restrict__ hist, const int* __restrict__ offs,
    const int* __restrict__ rowlist, const float* __restrict__ out_cnt,
    const double* __restrict__ nsum, float* __restrict__ out_emb,
    float* __restrict__ out_avg) {
#pragma clang fp contract(off)
  const int k = blockIdx.x;
  const int d = threadIdx.x;
  const int c = hist[k];
  const int off = offs[k];
  float s = 0.f;
  for (int j = 0; j < c; ++j)
    s += z[(size_t)rowlist[off + j] * kD + d];
  const size_t o = (size_t)k * kD + d;
  const float na = 0.99f * ea[o] + 0.01f * s;
  out_avg[o] = na;
  const float nf = (float)(*nsum);
  const float nc = out_cnt[k];
  const float keps = 0.08192f;  // fl(K * EPS)
  const float cs = (nc + 1e-5f) / (nf + keps) * nf;
  out_emb[o] = na / cs;
}

extern "C" void kernel_launch(void* const* d_in, const int* in_sizes, int n_in,
                              void* d_out, int out_size, void* d_ws, size_t ws_size,
                              hipStream_t stream) {
  const float* z_e       = (const float*)d_in[0];
  const float* embedding = (const float*)d_in[1];
  const float* ema_count = (const float*)d_in[2];
  const float* ema_avg   = (const float*)d_in[3];

  char* ws = (char*)d_ws;
  int*    hist   = (int*)(ws + OFF_HIST);
  double* nsum   = (double*)(ws + OFF_NS);
  unsigned* gcnt = (unsigned*)(ws + OFF_GCNT);
  int*    ccnt   = (int*)(ws + OFF_CCNT);
  unsigned long long* rkey = (unsigned long long*)(ws + OFF_RKEY);
  float*  sz     = (float*)(ws + OFF_SZ);
  float*  cw     = (float*)(ws + OFF_CW);
  _Float16* z16  = (_Float16*)(ws + OFF_Z16);
  _Float16* w16  = (_Float16*)(ws + OFF_W16);
  int2*   gcand  = (int2*)(ws + OFF_CAND);
  int2*   flat   = (int2*)(ws + OFF_FLAT);
  int*    idxg   = (int*)(ws + OFF_IDX);
  int*    offs   = (int*)(ws + OFF_OFFS);
  int*    cursor = (int*)(ws + OFF_CUR);
  int*    rowlist= (int*)(ws + OFF_ROWL);
  double* part   = (double*)(ws + OFF_PART);
  unsigned* rmin = (unsigned*)(ws + OFF_RKEY);  // unused alias silencer

  float* out_zq  = (float*)d_out;
  float* out_com = out_zq + (size_t)kN * kD;
  float* out_idx = out_com + 1;
  float* out_emb = out_idx + kN;
  float* out_cnt = out_emb + (size_t)kK * kD;
  float* out_avg = out_cnt + kK;

  // rmin_map shares the 0xFF-init region trick: use upper half of rkey? No —
  // rmin needs its own N*4. Reuse FLAT tail (init via memset below).
  unsigned* rmin_map = (unsigned*)(ws + OFF_FLAT + (size_t)FLATCAP * 8 - (size_t)kN * 4);
  (void)rmin;

  hipMemsetAsync(ws, 0, ZERO_BYTES, stream);
  hipMemsetAsync(ws + OFF_RKEY, 0xFF, FF_BYTES, stream);
  hipMemsetAsync((void*)rmin_map, 0xFF, (size_t)kN * 4, stream);

  rowsum_sq<<<kN / 256, 256, 0, stream>>>(z_e, sz);
  rowsum_sq<<<kK / 256, 256, 0, stream>>>(embedding, cw);
  tofp16<<<(kN * kD / 4) / 256, 256, 0, stream>>>(z_e, z16, 1.0f);
  tofp16<<<(kK * kD / 4) / 256, 256, 0, stream>>>(embedding, w16, 16384.0f);
  score_kernel<<<(kN / 64) * 4, 256, 0, stream>>>(z16, w16, cw, gcnt, gcand,
                                                  rmin_map);
  compact_kernel<<<kN / 4, 256, 0, stream>>>(gcnt, gcand, rmin_map, flat, ccnt);
  exact_kernel<<<1024, 256, 0, stream>>>(z_e, embedding, sz, cw, flat, ccnt,
                                         rkey);
  finalize_kernel<<<kN / 256, 256, 0, stream>>>(rkey, idxg, out_idx, hist);
  zq_commit<<<kN, 256, 0, stream>>>(z_e, embedding, idxg, out_zq, part);
  reduce_commit<<<1, 256, 0, stream>>>(part, out_com);
  newcount_k<<<kK / 256, 256, 0, stream>>>(hist, ema_count, out_cnt, nsum);
  prefix_k<<<1, 256, 0, stream>>>(hist, offs, cursor);
  scatter_k<<<kN / 256, 256, 0, stream>>>(idxg, cursor, rowlist);
  newavg_k<<<kK, 256, 0, stream>>>(z_e, ema_avg, hist, offs, rowlist, out_cnt,
                                   nsum, out_emb, out_avg);
}